// Round 14
// baseline (439.924 us; speedup 1.0000x reference)
//
#include <hip/hip_runtime.h>

// RuleFilter: out[0] = logits[0]; out[i] = logits[i] * mask_table[argmax(out[i-1])]
// logits: (L=128, N=4096, V=128) fp32, mask_table: (128,128) fp32 {0,1}.
// One wave per sequence n; lane holds vocab elems {2*lane, 2*lane+1}.
//
// FINAL (R14 = R11 = R4, the session's verified best: ~152 us dispatch,
// absmax 0.0 in two independent compilations/benches).
//
// Session ceiling arithmetic (R0-R13):
//  - A wave that waits on its own loads streams ~0.86 GB/s r+w, invariant
//    across ring depth (5-20), op width (256B-1KB: R4 vs R5 = same ops,
//    2x bytes, 2x step time -> bytes set the rate, not ops/waits),
//    occupancy (16-32 waves/CU: R8/R9), and store cache policy.
//  - 4096 independent chains -> max 4096 productive waves; helper-wave
//    schemes (lockstep split R8, decoupled dual-stream R9, LDS relay R10,
//    multi-kernel decomposition R7) all lose more to coordination or extra
//    traffic than they gain. Row-pair fusion (R12/R13) failed correctness
//    deterministically twice and its premise was already falsified by R5.
//  - 4096 x 0.86 GB/s = 3.5 TB/s logical over 537 MB -> ~152 us. This
//    kernel sits on that line; pure-copy roofline (85 us) is unreachable
//    for this dependence structure on this device.
//
// Structure: all-asm vmem pipeline (invisible to the backend's conservative
// waitcnt insertion), register ring D=20, exact per-step s_waitcnt vmcnt(N)
// (steady N=2D-2=38, never 0), plain (L2-acking) stores, ordering enforced
// by register ties rather than "memory" clobbers.

constexpr int V = 128;
constexpr int L = 128;
constexpr int N = 4096;
constexpr int D = 20;  // register ring depth (rows in flight); % D is constexpr
constexpr unsigned ROWB = (unsigned)N * V * 4;  // 2 MiB: byte stride between rows

typedef __attribute__((ext_vector_type(2))) float f32x2;

// Wave-wide max of x (all 64 lanes active), result broadcast to all lanes.
__device__ __forceinline__ float wave_max_dpp(float x) {
    int v = __float_as_int(x);
    const int ninf = __float_as_int(-__builtin_inff());
#define RF_STEP(ctrl)                                                          \
    {                                                                          \
        int s = __builtin_amdgcn_update_dpp(ninf, v, ctrl, 0xf, 0xf, false);   \
        v = __float_as_int(fmaxf(__int_as_float(v), __int_as_float(s)));       \
    }
    RF_STEP(0x111)  // row_shr:1
    RF_STEP(0x112)  // row_shr:2
    RF_STEP(0x114)  // row_shr:4
    RF_STEP(0x118)  // row_shr:8  -> lane 15 of each row16 has row max
    RF_STEP(0x142)  // row_bcast:15 -> lane31 = max(0..31), lane63 = max(32..63)
    RF_STEP(0x143)  // row_bcast:31 -> lane63 = max(all)
#undef RF_STEP
    return __int_as_float(__builtin_amdgcn_readlane(v, 63));
}

// argmax over the 128 values {f.x@2*lane, f.y@2*lane+1}; ties -> lowest index.
__device__ __forceinline__ int wave_argmax(f32x2 f) {
    const float bv = wave_max_dpp(fmaxf(f.x, f.y));
    unsigned long long b0 = __ballot(f.x == bv);
    unsigned long long b1 = __ballot(f.y == bv);
    int i0 = __ffsll(b0);  // 1-based, 0 if none
    int i1 = __ffsll(b1);
    int c0 = i0 ? (i0 - 1) * 2 : (1 << 30);
    int c1 = i1 ? (i1 - 1) * 2 + 1 : (1 << 30);
    return min(c0, c1);
}

// 8-way dynamic register select (j is wave-uniform; 7 cndmask/cselect ops).
__device__ __forceinline__ unsigned sel8(const unsigned* t, int j) {
    unsigned a0 = (j & 1) ? t[1] : t[0];
    unsigned a1 = (j & 1) ? t[3] : t[2];
    unsigned a2 = (j & 1) ? t[5] : t[4];
    unsigned a3 = (j & 1) ? t[7] : t[6];
    unsigned b0 = (j & 2) ? a1 : a0;
    unsigned b1 = (j & 2) ? a3 : a2;
    return (j & 4) ? b1 : b0;
}

// Wave-uniform pointer -> value the compiler KNOWS is uniform (SGPR-allocatable).
__device__ __forceinline__ unsigned long long uniform_u64(const void* p) {
    unsigned long long x = (unsigned long long)p;
    unsigned lo = __builtin_amdgcn_readfirstlane((unsigned)x);
    unsigned hi = __builtin_amdgcn_readfirstlane((unsigned)(x >> 32));
    return ((unsigned long long)hi << 32) | lo;
}

// One fully-unrolled pipeline step. All indices compile-time; ring/fbuf live
// entirely in VGPRs (SROA: every access has a constant index).
template <int I>
struct Step {
    static __device__ __forceinline__ void run(f32x2* ring, f32x2* fbuf,
                                               const unsigned* tbl, int& prev,
                                               unsigned long long lbase,
                                               unsigned long long obase,
                                               unsigned laneoff) {
        // Exact count of vmem ops issued after this slot's load (issue order
        // per step: wait, store S_I, load L_{I+D}):
        //   prologue region (I<=D-1): D-1+I
        //   steady (I<=L-D-1):        2D-2
        //   tail (loads exhausted):   D-1+(L-1-I)
        constexpr int NW = (I <= D - 1) ? (D - 1 + I)
                         : ((I <= L - D - 1) ? (2 * D - 2) : (D - 1 + (L - 1 - I)));
        constexpr int s  = I % D;

        // Wait until row I's load retired. Ties:
        //  %0 ring[s]  -> consumers below are data-ordered after the wait
        //  %1 fbuf[s]  -> keeps the D-iter-old store's data reg alive until
        //                 this wait (which provably retires that store)
        asm volatile("s_waitcnt vmcnt(%c2)"
                     : "+v"(ring[s])
                     : "v"(fbuf[s]), "i"(NW));

        f32x2 c = ring[s];
        f32x2 f;
        if (I == 0) {
            f = c;  // row 0 passes through unfiltered
        } else {
            const unsigned word  = sel8(tbl, prev >> 4);
            const unsigned fbits = (word >> ((prev & 15) * 2)) & 3u;
            f.x = (fbits & 1u) ? c.x : 0.0f;
            f.y = (fbits & 2u) ? c.y : 0.0f;
        }
        fbuf[s] = f;

        {
            unsigned voff = (unsigned)I * ROWB + laneoff;
            // Plain store (acks at L2); `nt` forced HBM-path acks and cost ~8%.
            asm volatile("global_store_dwordx2 %0, %1, %2"
                         :
                         : "v"(voff), "v"(fbuf[s]), "s"(obase));
        }

        prev = wave_argmax(f);

        if constexpr (I + D < L) {
            unsigned voff = (unsigned)(I + D) * ROWB + laneoff;
            asm volatile("global_load_dwordx2 %0, %1, %2"
                         : "=&v"(ring[s])
                         : "v"(voff), "s"(lbase));
        }

        Step<I + 1>::run(ring, fbuf, tbl, prev, lbase, obase, laneoff);
    }
};
template <>
struct Step<L> {
    static __device__ __forceinline__ void run(f32x2*, f32x2*, const unsigned*,
                                               int&, unsigned long long,
                                               unsigned long long, unsigned) {}
};

__global__ __launch_bounds__(256, 4) void rule_filter_kernel(
    const float* __restrict__ logits,      // (L, N, V)
    const float* __restrict__ mask_table,  // (V, V)
    float* __restrict__ out)               // (L, N, V)
{
    const int wave = threadIdx.x >> 6;  // 0..3
    const int lane = threadIdx.x & 63;  // 0..63
    const int n    = (blockIdx.x << 2) + wave;

    // Wave-uniform base pointers, laundered to SGPR-provable uniformity.
    const unsigned long long lbase = uniform_u64(logits + (size_t)n * V);
    const unsigned long long obase = uniform_u64(out    + (size_t)n * V);
    const unsigned laneoff = (unsigned)lane * 8;  // dwordx2 per lane

    // Per-lane mask table: tbl[j] bits(2r..2r+1) = mask_table[16j+r][2l..2l+1]
    unsigned tbl[8];
#pragma unroll 1
    for (int j = 0; j < 8; ++j) {
        unsigned acc = 0;
#pragma unroll
        for (int r = 0; r < 16; ++r) {
            const int p = j * 16 + r;
            float2 mv = *(const float2*)(mask_table + (size_t)p * V + lane * 2);
            acc |= ((mv.x != 0.0f ? 1u : 0u) | (mv.y != 0.0f ? 2u : 0u)) << (2 * r);
        }
        tbl[j] = acc;
    }
    // Drain table loads so the hand-counted vmcnt ledger is exact.
    asm volatile("s_waitcnt vmcnt(0)" ::: "memory");

    f32x2 ring[D];
    f32x2 fbuf[D];
#pragma unroll
    for (int r = 0; r < D; ++r) { fbuf[r].x = 0.0f; fbuf[r].y = 0.0f; }

    // Prologue: issue loads for rows 0..D-1 (in order; vmcnt ops 1..D).
#pragma unroll
    for (int r = 0; r < D; ++r) {
        unsigned voff = (unsigned)r * ROWB + laneoff;
        asm volatile("global_load_dwordx2 %0, %1, %2"
                     : "=&v"(ring[r])
                     : "v"(voff), "s"(lbase));
    }

    int prev = 0;
    Step<0>::run(ring, fbuf, tbl, prev, lbase, obase, laneoff);
}

extern "C" void kernel_launch(void* const* d_in, const int* in_sizes, int n_in,
                              void* d_out, int out_size, void* d_ws, size_t ws_size,
                              hipStream_t stream) {
    const float* logits     = (const float*)d_in[0];  // (L, N, V) fp32
    const float* mask_table = (const float*)d_in[1];  // (V, V) fp32
    float* out              = (float*)d_out;          // (L, N, V) fp32

    dim3 grid(N / 4);  // 4 sequences (waves) per 256-thread block
    dim3 block(256);
    rule_filter_kernel<<<grid, block, 0, stream>>>(logits, mask_table, out);
}